// Round 10
// baseline (271.255 us; speedup 1.0000x reference)
//
#include <hip/hip_runtime.h>
#include <hip/hip_bf16.h>

#define T_TOK 2048
#define H_DIM 1024
#define NEXP  16
#define I_DIM 512
#define CAP   384       // per-expert slot capacity (mean 256, sd ~15)
#define RSCALE 1.0f

typedef unsigned short u16;
typedef unsigned int   u32;
typedef __attribute__((ext_vector_type(4))) float  f32x4;
typedef __attribute__((ext_vector_type(8))) __bf16 bf16x8;
typedef __attribute__((ext_vector_type(8))) u16    u16x8;
typedef __attribute__((ext_vector_type(4))) u16    u16x4;

__device__ __forceinline__ u16 f2bf(float f) {
  u32 u = __builtin_bit_cast(u32, f);
  u32 r = u + 0x7fffu + ((u >> 16) & 1u);   // RNE
  return (u16)(r >> 16);
}
__device__ __forceinline__ float bf2f(u16 h) {
  return __builtin_bit_cast(float, (u32)h << 16);
}
__device__ __forceinline__ void gload16(const void* g, void* l) {
  __builtin_amdgcn_global_load_lds((const __attribute__((address_space(1))) u32*)g,
                                   (__attribute__((address_space(3))) u32*)l, 16, 0, 0);
}

// ---------------- convert fp32 -> bf16, transposing B operands to [N][K] ----------------
// rmul=2 interleaves gate/up rows: source col i of matrix `mat` -> dst row 2i+mat,
// so the GU-GEMM's C fragments hold gate (even lanes) / up (odd lanes) pairs.
__device__ __forceinline__ void transpose_tile(const float* __restrict__ src, int srcN,
                                               int k0, int n0,
                                               u16* __restrict__ dst, int dstride,
                                               int drow0, int rmul)
{
  __shared__ float t[64][65];
  int tid = threadIdx.x;
  int kl = tid >> 4, c4 = (tid & 15) * 4;
  #pragma unroll
  for (int p = 0; p < 4; ++p) {
    f32x4 v = *(const f32x4*)(src + (size_t)(k0 + p*16 + kl) * srcN + n0 + c4);
    #pragma unroll
    for (int j = 0; j < 4; ++j) t[p*16 + kl][c4 + j] = v[j];
  }
  __syncthreads();
  int nl = tid >> 3, kc = (tid & 7) * 8;
  #pragma unroll
  for (int p = 0; p < 2; ++p) {
    int n = p*32 + nl;
    u16x8 o;
    #pragma unroll
    for (int j = 0; j < 8; ++j) o[j] = f2bf(t[kc + j][n]);
    *(u16x8*)(dst + (size_t)(drow0 + n*rmul) * dstride + k0 + kc) = o;
  }
}

__global__ __launch_bounds__(256) void convert_kernel(
    const float* __restrict__ x,
    const float* __restrict__ w_gate, const float* __restrict__ w_up,
    const float* __restrict__ w_down,
    const float* __restrict__ wsg, const float* __restrict__ wsu,
    const float* __restrict__ wsd,
    u16* __restrict__ xb, u16* __restrict__ wgu_t, u16* __restrict__ wd_t,
    u16* __restrict__ wsgu_t, u16* __restrict__ wsd_t)
{
  int tile = blockIdx.x, tid = threadIdx.x;
  if (tile < 512) {                       // x: straight convert
    #pragma unroll
    for (int p = 0; p < 4; ++p) {
      int fi = tile*1024 + p*256 + tid;
      f32x4 v = ((const f32x4*)x)[fi];
      u16x4 o;
      #pragma unroll
      for (int j = 0; j < 4; ++j) o[j] = f2bf(v[j]);
      ((u16x4*)xb)[fi] = o;
    }
  } else if (tile < 4608) {               // w_gate|w_up -> wgu_t[e], rows 2i+mat (interleaved)
    int t2 = tile - 512; int e = t2 >> 8; int r = t2 & 255;
    int mat = r >> 7; int q = r & 127; int kt = q >> 3, nt = q & 7;
    const float* src = (mat ? w_up : w_gate) + (size_t)e * H_DIM * I_DIM;
    transpose_tile(src, I_DIM, kt*64, nt*64,
                   wgu_t + (size_t)e * 1024 * 1024, 1024, nt*128 + mat, 2);
  } else if (tile < 6656) {               // w_down -> wd_t[e][1024(n=H)][512(k=I)]
    int t2 = tile - 4608; int e = t2 >> 7; int q = t2 & 127;
    int kt = q >> 4, nt = q & 15;
    transpose_tile(w_down + (size_t)e * I_DIM * H_DIM, H_DIM, kt*64, nt*64,
                   wd_t + (size_t)e * 1024 * 512, 512, nt*64, 1);
  } else if (tile < 7168) {               // ws_gate|ws_up -> wsgu_t, rows 2i+mat (interleaved)
    int t2 = tile - 6656; int mat = t2 >> 8; int q = t2 & 255;
    int kt = q >> 4, nt = q & 15;
    transpose_tile(mat ? wsu : wsg, 1024, kt*64, nt*64,
                   wsgu_t, 1024, nt*128 + mat, 2);
  } else {                                // ws_down -> wsd_t[1024(n=H)][1024(k=IS)]
    int t2 = tile - 7168; int kt = t2 >> 4, nt = t2 & 15;
    transpose_tile(wsd, H_DIM, kt*64, nt*64, wsd_t, 1024, nt*64, 1);
  }
}

// ---------------- router (unchanged, proven) ----------------
__global__ __launch_bounds__(256) void router_kernel(
    const float* __restrict__ x, const float* __restrict__ gw,
    int* __restrict__ perm_tok, int* __restrict__ slot_of,
    float* __restrict__ tok_w, int* __restrict__ counts)
{
  __shared__ f32x4 gws[4096];             // 64 KB linear copy of gate_w
  int tid = threadIdx.x;
  const f32x4* gw4 = (const f32x4*)gw;
  #pragma unroll
  for (int i = 0; i < 16; ++i) gws[i*256 + tid] = gw4[i*256 + tid];
  __syncthreads();

  int wv = tid >> 6, l = tid & 63;
  int t0 = blockIdx.x * 16 + wv * 4;

  f32x4 xv[4][4];
  #pragma unroll
  for (int tk = 0; tk < 4; ++tk) {
    const f32x4* xr = (const f32x4*)(x + (size_t)(t0 + tk) * H_DIM);
    #pragma unroll
    for (int j = 0; j < 4; ++j) xv[tk][j] = xr[j*64 + l];
  }

  float p[4][NEXP];
  #pragma unroll
  for (int tk = 0; tk < 4; ++tk)
    #pragma unroll
    for (int e = 0; e < NEXP; ++e) p[tk][e] = 0.f;

  #pragma unroll
  for (int j = 0; j < 4; ++j)
    #pragma unroll
    for (int e = 0; e < NEXP; ++e) {
      f32x4 g = gws[e*256 + j*64 + l];
      #pragma unroll
      for (int tk = 0; tk < 4; ++tk)
        p[tk][e] += xv[tk][j][0]*g[0] + xv[tk][j][1]*g[1]
                  + xv[tk][j][2]*g[2] + xv[tk][j][3]*g[3];
    }

  #pragma unroll
  for (int tk = 0; tk < 4; ++tk)
    #pragma unroll
    for (int e = 0; e < NEXP; ++e)
      #pragma unroll
      for (int off = 32; off; off >>= 1)
        p[tk][e] += __shfl_xor(p[tk][e], off);

  if (l < 4) {
    int tk = l;
    int t = t0 + tk;
    float m = p[tk][0];
    #pragma unroll
    for (int e = 1; e < NEXP; ++e) m = fmaxf(m, p[tk][e]);
    float q[NEXP]; float s = 0.f;
    #pragma unroll
    for (int e = 0; e < NEXP; ++e) { q[e] = expf(p[tk][e] - m); s += q[e]; }
    float inv = 1.f / s;
    int e1 = 0; float b1 = -1.f;
    #pragma unroll
    for (int e = 0; e < NEXP; ++e) if (q[e] > b1) { b1 = q[e]; e1 = e; }
    int e2 = -1; float b2 = -1.f;
    #pragma unroll
    for (int e = 0; e < NEXP; ++e) if (e != e1 && q[e] > b2) { b2 = q[e]; e2 = e; }

    tok_w[2*t]   = b1 * inv * RSCALE;
    tok_w[2*t+1] = b2 * inv * RSCALE;
    int p1 = atomicAdd(&counts[e1], 1);
    if (p1 < CAP) { perm_tok[e1*CAP + p1] = t; slot_of[2*t] = e1*CAP + p1; }
    else slot_of[2*t] = -1;
    int p2 = atomicAdd(&counts[e2], 1);
    if (p2 < CAP) { perm_tok[e2*CAP + p2] = t; slot_of[2*t+1] = e2*CAP + p2; }
    else slot_of[2*t+1] = -1;
  }
}

// ---------------- fused bf16 MFMA GEMM (routed + shared in ONE dispatch) ----------------
// GU=true: gate|up with B rows interleaved (even=gate, odd=up); epilogue computes
//   silu(g)*u via lane-pair shfl on the f32 accumulators and stores bf16 act
//   (half-width: cstr = NMAT/2). silumul kernel is GONE.
// GU=false: down-proj, f32 store (unchanged).
// Grid (1D): blocks [0,384) routed; rest shared (GU: 640 total; DOWN: 512).
template<bool GU>
__global__ __launch_bounds__(256, 2) void gemm_fused_kernel(
    const u16* __restrict__ A_sh, const u16* __restrict__ A_rt,
    const u16* __restrict__ B_sh, const u16* __restrict__ B_rt,
    u16* __restrict__ C_sh, u16* __restrict__ C_rt,
    float* __restrict__ O_sh, float* __restrict__ O_rt,
    const int* __restrict__ counts, const int* __restrict__ perm_tok)
{
  int b = blockIdx.x;
  bool routed = b < 384;

  int kdim, m0, m_end, n0, cstr;
  const u16 *A, *B;
  u16* C; float* O;
  bool gather = false;

  if (routed) {
    int e  = b / 24;
    int r  = b % 24;
    int my = r >> 3, nx = r & 7;
    int cnt = counts[e]; if (cnt > CAP) cnt = CAP;
    int m_start = e * CAP;
    m_end = m_start + cnt;
    m0 = m_start + my * 128;
    if (m0 >= m_end) return;
    n0 = nx * 128;
    if (GU) {
      kdim = 1024; A = A_rt; gather = true;
      B = B_rt + ((size_t)e << 20);            // wgu_t[e]: 1024x1024 (interleaved rows)
      C = C_rt; cstr = 512; O = nullptr;       // act_r, width I_DIM
    } else {
      kdim = 512;  A = A_rt;                   // act_r slot rows, stride 512
      B = B_rt + ((size_t)e << 19);            // wd_t[e]: 1024x512
      C = nullptr; cstr = 0; O = O_rt;         // down_r, stride H_DIM
    }
  } else {
    int s = b - 384;
    kdim = 1024;
    if (GU) {
      int my = s >> 4, nx = s & 15;            // C 2048x2048 -> act 2048x1024
      m0 = my * 128; n0 = nx * 128; m_end = T_TOK;
      A = A_sh; B = B_sh; C = C_sh; cstr = 1024; O = nullptr;
    } else {
      int my = s >> 3, nx = s & 7;             // 2048x1024, 16x8 tiles
      m0 = my * 128; n0 = nx * 128; m_end = T_TOK;
      A = A_sh; B = B_sh; C = nullptr; cstr = 0; O = O_sh;
    }
  }

  __shared__ __align__(16) u16 lds[2][2][8192];   // [buf][A/B][128x64]
  int tid = threadIdx.x;
  int wv = tid >> 6, l = tid & 63;
  int wm = wv >> 1, wn = wv & 1;
  int rl = tid >> 3;            // staging row 0..31
  int c8 = (tid & 7) * 8;       // staging col (elements)

  f32x4 acc[4][4];
  #pragma unroll
  for (int m = 0; m < 4; ++m)
    #pragma unroll
    for (int n = 0; n < 4; ++n) acc[m][n] = f32x4{0.f, 0.f, 0.f, 0.f};

  auto stage = [&](int buf, int kt) {
    int k0 = kt * 64;
    #pragma unroll
    for (int i = 0; i < 4; ++i) {
      int slot = m0 + i*32 + rl;
      int srow = slot < m_end ? slot : m_end - 1;
      int grow = gather ? perm_tok[srow] : srow;
      gload16(A + (size_t)grow * kdim + k0 + c8, &lds[buf][0][i*2048 + wv*512]);
    }
    #pragma unroll
    for (int i = 0; i < 4; ++i) {
      gload16(B + (size_t)(n0 + i*32 + rl) * kdim + k0 + c8, &lds[buf][1][i*2048 + wv*512]);
    }
  };

  stage(0, 0);
  __syncthreads();
  const int NK = kdim >> 6;
  for (int kt = 0; kt < NK; ++kt) {
    int buf = kt & 1;
    if (kt + 1 < NK) stage(buf ^ 1, kt + 1);
    const u16* At  = &lds[buf][0][0];
    const u16* Btl = &lds[buf][1][0];
    #pragma unroll
    for (int kk = 0; kk < 2; ++kk) {
      bf16x8 af[4], bv[4];
      int ko = kk*32 + (l >> 4) * 8;
      #pragma unroll
      for (int m = 0; m < 4; ++m)
        af[m] = *(const bf16x8*)(At + (wm*64 + m*16 + (l & 15)) * 64 + ko);
      #pragma unroll
      for (int n = 0; n < 4; ++n)
        bv[n] = *(const bf16x8*)(Btl + (wn*64 + n*16 + (l & 15)) * 64 + ko);
      #pragma unroll
      for (int m = 0; m < 4; ++m)
        #pragma unroll
        for (int n = 0; n < 4; ++n)
          acc[m][n] = __builtin_amdgcn_mfma_f32_16x16x32_bf16(af[m], bv[n], acc[m][n], 0, 0, 0);
    }
    __syncthreads();
  }

  #pragma unroll
  for (int m = 0; m < 4; ++m) {
    #pragma unroll
    for (int n = 0; n < 4; ++n) {
      int col = n0 + wn*64 + n*16 + (l & 15);
      #pragma unroll
      for (int r = 0; r < 4; ++r) {
        int slot = m0 + wm*64 + m*16 + (l >> 4)*4 + r;
        if (GU) {
          // lane pair (l even, l odd) holds (gate, up) for act col = col>>1.
          float own = acc[m][n][r];
          float oth = __shfl_xor(own, 1);
          float g = (l & 1) ? oth : own;
          float u = (l & 1) ? own : oth;
          float actv = g / (1.f + expf(-g)) * u;
          if (!(l & 1) && slot < m_end)
            C[(size_t)slot * cstr + (col >> 1)] = f2bf(actv);
        } else {
          if (slot < m_end)
            O[(size_t)slot * H_DIM + col] = acc[m][n][r];
        }
      }
    }
  }
}

// ---------------- final combine: out = shared + w0*row(s0) + w1*row(s1) ----------------
__global__ __launch_bounds__(256) void combine_kernel(
    float* __restrict__ out, const float* __restrict__ down_r,
    const int* __restrict__ slot_of, const float* __restrict__ tok_w)
{
  int t = blockIdx.x, c = threadIdx.x;
  f32x4* orow = (f32x4*)(out + (size_t)t * H_DIM);
  f32x4 o = orow[c];
  int s0 = slot_of[2*t], s1 = slot_of[2*t+1];
  float w0 = tok_w[2*t], w1 = tok_w[2*t+1];
  if (s0 >= 0) {
    f32x4 v = ((const f32x4*)(down_r + (size_t)s0 * H_DIM))[c];
    o += v * w0;
  }
  if (s1 >= 0) {
    f32x4 v = ((const f32x4*)(down_r + (size_t)s1 * H_DIM))[c];
    o += v * w1;
  }
  orow[c] = o;
}

extern "C" void kernel_launch(void* const* d_in, const int* in_sizes, int n_in,
                              void* d_out, int out_size, void* d_ws, size_t ws_size,
                              hipStream_t stream)
{
  (void)in_sizes; (void)n_in; (void)out_size;
  const float* x       = (const float*)d_in[0];
  const float* gate_w  = (const float*)d_in[1];
  const float* w_gate  = (const float*)d_in[2];
  const float* w_up    = (const float*)d_in[3];
  const float* w_down  = (const float*)d_in[4];
  const float* wsg     = (const float*)d_in[5];
  const float* wsu     = (const float*)d_in[6];
  const float* wsd     = (const float*)d_in[7];
  float* out = (float*)d_out;

  char* base = (char*)d_ws;
  size_t off = 0;
  auto alloc = [&](size_t n) -> void* {
    void* r = base + off;
    off += (n + 255) & ~(size_t)255;
    return r;
  };
  u16* xb       = (u16*)alloc((size_t)T_TOK * H_DIM * 2);            //  4 MiB
  u16* wgu_t    = (u16*)alloc((size_t)NEXP * 1024 * 1024 * 2);       // 32 MiB
  u16* wd_t     = (u16*)alloc((size_t)NEXP * 1024 * 512 * 2);        // 16 MiB
  u16* wsgu_t   = (u16*)alloc((size_t)2048 * 1024 * 2);              //  4 MiB
  u16* wsd_t    = (u16*)alloc((size_t)1024 * 1024 * 2);              //  2 MiB
  u16* act_r    = (u16*)alloc((size_t)NEXP * CAP * I_DIM * 2);       //  6 MiB
  u16* act_s    = (u16*)alloc((size_t)T_TOK * 1024 * 2);             //  4 MiB
  int*   counts   = (int*)alloc(64);
  int*   tok_w_i  = (int*)alloc((size_t)2 * T_TOK * 4);
  int*   slot_of  = (int*)alloc((size_t)2 * T_TOK * 4);
  int*   perm_tok = (int*)alloc((size_t)NEXP * CAP * 4);
  float* tok_w = (float*)tok_w_i;
  // alias: down_r (16x384 rows x 1024 f32 = 24 MiB) reuses wgu_t, whose last
  // reader is the GU GEMM that strictly precedes the DOWN GEMM on this stream.
  float* down_r = (float*)wgu_t;
  if (off > ws_size) return;   // fail loudly rather than corrupt

  hipMemsetAsync(counts, 0, 64, stream);
  convert_kernel<<<7424, 256, 0, stream>>>(x, w_gate, w_up, w_down, wsg, wsu, wsd,
                                           xb, wgu_t, wd_t, wsgu_t, wsd_t);
  router_kernel<<<128, 256, 0, stream>>>(x, gate_w, perm_tok, slot_of, tok_w, counts);
  // fused gate|up + SwiGLU: routed -> act_r, shared -> act_s (no gu intermediate)
  gemm_fused_kernel<true><<<640, 256, 0, stream>>>(
      xb, xb, wsgu_t, wgu_t, act_s, act_r, nullptr, nullptr, counts, perm_tok);
  // fused down: routed (A=act_r, B=wd_t, O=down_r) + shared (A=act_s, B=wsd_t, O=out)
  gemm_fused_kernel<false><<<512, 256, 0, stream>>>(
      act_s, act_r, wsd_t, wd_t, nullptr, nullptr, out, down_r, counts, perm_tok);
  combine_kernel<<<T_TOK, 256, 0, stream>>>(out, down_r, slot_of, tok_w);
}

// Round 12
// 253.452 us; speedup vs baseline: 1.0702x; 1.0702x over previous
//
#include <hip/hip_runtime.h>
#include <hip/hip_bf16.h>

#define T_TOK 2048
#define H_DIM 1024
#define NEXP  16
#define I_DIM 512
#define CAP   384       // per-expert slot capacity (mean 256, sd ~15)
#define RSCALE 1.0f

typedef unsigned short u16;
typedef unsigned int   u32;
typedef __attribute__((ext_vector_type(4))) float  f32x4;
typedef __attribute__((ext_vector_type(8))) __bf16 bf16x8;
typedef __attribute__((ext_vector_type(8))) u16    u16x8;
typedef __attribute__((ext_vector_type(4))) u16    u16x4;

__device__ __forceinline__ u16 f2bf(float f) {
  u32 u = __builtin_bit_cast(u32, f);
  u32 r = u + 0x7fffu + ((u >> 16) & 1u);   // RNE
  return (u16)(r >> 16);
}
__device__ __forceinline__ float bf2f(u16 h) {
  return __builtin_bit_cast(float, (u32)h << 16);
}
__device__ __forceinline__ void gload16(const void* g, void* l) {
  __builtin_amdgcn_global_load_lds((const __attribute__((address_space(1))) u32*)g,
                                   (__attribute__((address_space(3))) u32*)l, 16, 0, 0);
}

// ---------------- convert fp32 -> bf16, transposing B operands to [N][K] ----------------
// rmul=2 interleaves gate/up rows: source col i of matrix `mat` -> dst row 2i+mat,
// so the GU-GEMM's C fragments hold gate (even lanes) / up (odd lanes) pairs.
__device__ __forceinline__ void transpose_tile(const float* __restrict__ src, int srcN,
                                               int k0, int n0,
                                               u16* __restrict__ dst, int dstride,
                                               int drow0, int rmul)
{
  __shared__ float t[64][65];
  int tid = threadIdx.x;
  int kl = tid >> 4, c4 = (tid & 15) * 4;
  #pragma unroll
  for (int p = 0; p < 4; ++p) {
    f32x4 v = *(const f32x4*)(src + (size_t)(k0 + p*16 + kl) * srcN + n0 + c4);
    #pragma unroll
    for (int j = 0; j < 4; ++j) t[p*16 + kl][c4 + j] = v[j];
  }
  __syncthreads();
  int nl = tid >> 3, kc = (tid & 7) * 8;
  #pragma unroll
  for (int p = 0; p < 2; ++p) {
    int n = p*32 + nl;
    u16x8 o;
    #pragma unroll
    for (int j = 0; j < 8; ++j) o[j] = f2bf(t[kc + j][n]);
    *(u16x8*)(dst + (size_t)(drow0 + n*rmul) * dstride + k0 + kc) = o;
  }
}

__global__ __launch_bounds__(256) void convert_kernel(
    const float* __restrict__ x,
    const float* __restrict__ w_gate, const float* __restrict__ w_up,
    const float* __restrict__ w_down,
    const float* __restrict__ wsg, const float* __restrict__ wsu,
    const float* __restrict__ wsd,
    u16* __restrict__ xb, u16* __restrict__ wgu_t, u16* __restrict__ wd_t,
    u16* __restrict__ wsgu_t, u16* __restrict__ wsd_t)
{
  int tile = blockIdx.x, tid = threadIdx.x;
  if (tile < 512) {                       // x: straight convert
    #pragma unroll
    for (int p = 0; p < 4; ++p) {
      int fi = tile*1024 + p*256 + tid;
      f32x4 v = ((const f32x4*)x)[fi];
      u16x4 o;
      #pragma unroll
      for (int j = 0; j < 4; ++j) o[j] = f2bf(v[j]);
      ((u16x4*)xb)[fi] = o;
    }
  } else if (tile < 4608) {               // w_gate|w_up -> wgu_t[e], rows 2i+mat (interleaved)
    int t2 = tile - 512; int e = t2 >> 8; int r = t2 & 255;
    int mat = r >> 7; int q = r & 127; int kt = q >> 3, nt = q & 7;
    const float* src = (mat ? w_up : w_gate) + (size_t)e * H_DIM * I_DIM;
    transpose_tile(src, I_DIM, kt*64, nt*64,
                   wgu_t + (size_t)e * 1024 * 1024, 1024, nt*128 + mat, 2);
  } else if (tile < 6656) {               // w_down -> wd_t[e][1024(n=H)][512(k=I)]
    int t2 = tile - 4608; int e = t2 >> 7; int q = t2 & 127;
    int kt = q >> 4, nt = q & 15;
    transpose_tile(w_down + (size_t)e * I_DIM * H_DIM, H_DIM, kt*64, nt*64,
                   wd_t + (size_t)e * 1024 * 512, 512, nt*64, 1);
  } else if (tile < 7168) {               // ws_gate|ws_up -> wsgu_t, rows 2i+mat (interleaved)
    int t2 = tile - 6656; int mat = t2 >> 8; int q = t2 & 255;
    int kt = q >> 4, nt = q & 15;
    transpose_tile(mat ? wsu : wsg, 1024, kt*64, nt*64,
                   wsgu_t, 1024, nt*128 + mat, 2);
  } else {                                // ws_down -> wsd_t[1024(n=H)][1024(k=IS)]
    int t2 = tile - 7168; int kt = t2 >> 4, nt = t2 & 15;
    transpose_tile(wsd, H_DIM, kt*64, nt*64, wsd_t, 1024, nt*64, 1);
  }
}

// ---------------- router (unchanged, proven) ----------------
__global__ __launch_bounds__(256) void router_kernel(
    const float* __restrict__ x, const float* __restrict__ gw,
    int* __restrict__ perm_tok, int* __restrict__ slot_of,
    float* __restrict__ tok_w, int* __restrict__ counts)
{
  __shared__ f32x4 gws[4096];             // 64 KB linear copy of gate_w
  int tid = threadIdx.x;
  const f32x4* gw4 = (const f32x4*)gw;
  #pragma unroll
  for (int i = 0; i < 16; ++i) gws[i*256 + tid] = gw4[i*256 + tid];
  __syncthreads();

  int wv = tid >> 6, l = tid & 63;
  int t0 = blockIdx.x * 16 + wv * 4;

  f32x4 xv[4][4];
  #pragma unroll
  for (int tk = 0; tk < 4; ++tk) {
    const f32x4* xr = (const f32x4*)(x + (size_t)(t0 + tk) * H_DIM);
    #pragma unroll
    for (int j = 0; j < 4; ++j) xv[tk][j] = xr[j*64 + l];
  }

  float p[4][NEXP];
  #pragma unroll
  for (int tk = 0; tk < 4; ++tk)
    #pragma unroll
    for (int e = 0; e < NEXP; ++e) p[tk][e] = 0.f;

  #pragma unroll
  for (int j = 0; j < 4; ++j)
    #pragma unroll
    for (int e = 0; e < NEXP; ++e) {
      f32x4 g = gws[e*256 + j*64 + l];
      #pragma unroll
      for (int tk = 0; tk < 4; ++tk)
        p[tk][e] += xv[tk][j][0]*g[0] + xv[tk][j][1]*g[1]
                  + xv[tk][j][2]*g[2] + xv[tk][j][3]*g[3];
    }

  #pragma unroll
  for (int tk = 0; tk < 4; ++tk)
    #pragma unroll
    for (int e = 0; e < NEXP; ++e)
      #pragma unroll
      for (int off = 32; off; off >>= 1)
        p[tk][e] += __shfl_xor(p[tk][e], off);

  if (l < 4) {
    int tk = l;
    int t = t0 + tk;
    float m = p[tk][0];
    #pragma unroll
    for (int e = 1; e < NEXP; ++e) m = fmaxf(m, p[tk][e]);
    float q[NEXP]; float s = 0.f;
    #pragma unroll
    for (int e = 0; e < NEXP; ++e) { q[e] = expf(p[tk][e] - m); s += q[e]; }
    float inv = 1.f / s;
    int e1 = 0; float b1 = -1.f;
    #pragma unroll
    for (int e = 0; e < NEXP; ++e) if (q[e] > b1) { b1 = q[e]; e1 = e; }
    int e2 = -1; float b2 = -1.f;
    #pragma unroll
    for (int e = 0; e < NEXP; ++e) if (e != e1 && q[e] > b2) { b2 = q[e]; e2 = e; }

    tok_w[2*t]   = b1 * inv * RSCALE;
    tok_w[2*t+1] = b2 * inv * RSCALE;
    int p1 = atomicAdd(&counts[e1], 1);
    if (p1 < CAP) { perm_tok[e1*CAP + p1] = t; slot_of[2*t] = e1*CAP + p1; }
    else slot_of[2*t] = -1;
    int p2 = atomicAdd(&counts[e2], 1);
    if (p2 < CAP) { perm_tok[e2*CAP + p2] = t; slot_of[2*t+1] = e2*CAP + p2; }
    else slot_of[2*t+1] = -1;
  }
}

// ---------------- fused bf16 MFMA GEMM (routed + shared in ONE dispatch) ----------------
// PENDING EXPERIMENT (R10->R11): BK 64 -> 32. LDS 64 KB -> 32 KB per block, lifting
// the occupancy cap from 2 to ~4-5 blocks/CU so co-resident blocks cover the
// per-K-step vmcnt(0)+barrier drain (R10 counters: Occupancy 12%, MfmaUtil 11.5%).
// GU=true: gate|up interleaved B rows; epilogue = silu(g)*u via lane-pair shfl.
// GU=false: down-proj, f32 store. Grid: blocks [0,384) routed; rest shared.
template<bool GU>
__global__ __launch_bounds__(256, 4) void gemm_fused_kernel(
    const u16* __restrict__ A_sh, const u16* __restrict__ A_rt,
    const u16* __restrict__ B_sh, const u16* __restrict__ B_rt,
    u16* __restrict__ C_sh, u16* __restrict__ C_rt,
    float* __restrict__ O_sh, float* __restrict__ O_rt,
    const int* __restrict__ counts, const int* __restrict__ perm_tok)
{
  int b = blockIdx.x;
  bool routed = b < 384;

  int kdim, m0, m_end, n0, cstr;
  const u16 *A, *B;
  u16* C; float* O;
  bool gather = false;

  if (routed) {
    int e  = b / 24;
    int r  = b % 24;
    int my = r >> 3, nx = r & 7;
    int cnt = counts[e]; if (cnt > CAP) cnt = CAP;
    int m_start = e * CAP;
    m_end = m_start + cnt;
    m0 = m_start + my * 128;
    if (m0 >= m_end) return;
    n0 = nx * 128;
    if (GU) {
      kdim = 1024; A = A_rt; gather = true;
      B = B_rt + ((size_t)e << 20);            // wgu_t[e]: 1024x1024 (interleaved rows)
      C = C_rt; cstr = 512; O = nullptr;       // act_r, width I_DIM
    } else {
      kdim = 512;  A = A_rt;                   // act_r slot rows, stride 512
      B = B_rt + ((size_t)e << 19);            // wd_t[e]: 1024x512
      C = nullptr; cstr = 0; O = O_rt;         // down_r, stride H_DIM
    }
  } else {
    int s = b - 384;
    kdim = 1024;
    if (GU) {
      int my = s >> 4, nx = s & 15;            // C 2048x2048 -> act 2048x1024
      m0 = my * 128; n0 = nx * 128; m_end = T_TOK;
      A = A_sh; B = B_sh; C = C_sh; cstr = 1024; O = nullptr;
    } else {
      int my = s >> 3, nx = s & 7;             // 2048x1024, 16x8 tiles
      m0 = my * 128; n0 = nx * 128; m_end = T_TOK;
      A = A_sh; B = B_sh; C = nullptr; cstr = 0; O = O_sh;
    }
  }

  __shared__ __align__(16) u16 lds[2][2][4096];   // [buf][A/B][128x32] = 32 KB total
  int tid = threadIdx.x;
  int wv = tid >> 6, l = tid & 63;
  int wm = wv >> 1, wn = wv & 1;
  int rl = tid >> 2;            // staging row 0..63 (4 lanes/row)
  int c4e = (tid & 3) * 8;      // staging col (elements, 4x8=32)

  f32x4 acc[4][4];
  #pragma unroll
  for (int m = 0; m < 4; ++m)
    #pragma unroll
    for (int n = 0; n < 4; ++n) acc[m][n] = f32x4{0.f, 0.f, 0.f, 0.f};

  auto stage = [&](int buf, int kt) {
    int k0 = kt * 32;
    #pragma unroll
    for (int i = 0; i < 2; ++i) {            // two 64-row halves of the 128-row A tile
      int slot = m0 + i*64 + rl;
      int srow = slot < m_end ? slot : m_end - 1;
      int grow = gather ? perm_tok[srow] : srow;
      gload16(A + (size_t)grow * kdim + k0 + c4e, &lds[buf][0][i*2048 + wv*512]);
    }
    #pragma unroll
    for (int i = 0; i < 2; ++i) {
      gload16(B + (size_t)(n0 + i*64 + rl) * kdim + k0 + c4e, &lds[buf][1][i*2048 + wv*512]);
    }
  };

  stage(0, 0);
  __syncthreads();
  const int NK = kdim >> 5;
  for (int kt = 0; kt < NK; ++kt) {
    int buf = kt & 1;
    if (kt + 1 < NK) stage(buf ^ 1, kt + 1);
    const u16* At  = &lds[buf][0][0];
    const u16* Btl = &lds[buf][1][0];
    bf16x8 af[4], bv[4];
    int ko = (l >> 4) * 8;
    #pragma unroll
    for (int m = 0; m < 4; ++m)
      af[m] = *(const bf16x8*)(At + (wm*64 + m*16 + (l & 15)) * 32 + ko);
    #pragma unroll
    for (int n = 0; n < 4; ++n)
      bv[n] = *(const bf16x8*)(Btl + (wn*64 + n*16 + (l & 15)) * 32 + ko);
    #pragma unroll
    for (int m = 0; m < 4; ++m)
      #pragma unroll
      for (int n = 0; n < 4; ++n)
        acc[m][n] = __builtin_amdgcn_mfma_f32_16x16x32_bf16(af[m], bv[n], acc[m][n], 0, 0, 0);
    __syncthreads();
  }

  #pragma unroll
  for (int m = 0; m < 4; ++m) {
    #pragma unroll
    for (int n = 0; n < 4; ++n) {
      int col = n0 + wn*64 + n*16 + (l & 15);
      #pragma unroll
      for (int r = 0; r < 4; ++r) {
        int slot = m0 + wm*64 + m*16 + (l >> 4)*4 + r;
        if (GU) {
          // lane pair (l even, l odd) holds (gate, up) for act col = col>>1.
          float own = acc[m][n][r];
          float oth = __shfl_xor(own, 1);
          float g = (l & 1) ? oth : own;
          float u = (l & 1) ? own : oth;
          float actv = g / (1.f + expf(-g)) * u;
          if (!(l & 1) && slot < m_end)
            C[(size_t)slot * cstr + (col >> 1)] = f2bf(actv);
        } else {
          if (slot < m_end)
            O[(size_t)slot * H_DIM + col] = acc[m][n][r];
        }
      }
    }
  }
}

// ---------------- final combine: out = shared + w0*row(s0) + w1*row(s1) ----------------
__global__ __launch_bounds__(256) void combine_kernel(
    float* __restrict__ out, const float* __restrict__ down_r,
    const int* __restrict__ slot_of, const float* __restrict__ tok_w)
{
  int t = blockIdx.x, c = threadIdx.x;
  f32x4* orow = (f32x4*)(out + (size_t)t * H_DIM);
  f32x4 o = orow[c];
  int s0 = slot_of[2*t], s1 = slot_of[2*t+1];
  float w0 = tok_w[2*t], w1 = tok_w[2*t+1];
  if (s0 >= 0) {
    f32x4 v = ((const f32x4*)(down_r + (size_t)s0 * H_DIM))[c];
    o += v * w0;
  }
  if (s1 >= 0) {
    f32x4 v = ((const f32x4*)(down_r + (size_t)s1 * H_DIM))[c];
    o += v * w1;
  }
  orow[c] = o;
}

extern "C" void kernel_launch(void* const* d_in, const int* in_sizes, int n_in,
                              void* d_out, int out_size, void* d_ws, size_t ws_size,
                              hipStream_t stream)
{
  (void)in_sizes; (void)n_in; (void)out_size;
  const float* x       = (const float*)d_in[0];
  const float* gate_w  = (const float*)d_in[1];
  const float* w_gate  = (const float*)d_in[2];
  const float* w_up    = (const float*)d_in[3];
  const float* w_down  = (const float*)d_in[4];
  const float* wsg     = (const float*)d_in[5];
  const float* wsu     = (const float*)d_in[6];
  const float* wsd     = (const float*)d_in[7];
  float* out = (float*)d_out;

  char* base = (char*)d_ws;
  size_t off = 0;
  auto alloc = [&](size_t n) -> void* {
    void* r = base + off;
    off += (n + 255) & ~(size_t)255;
    return r;
  };
  u16* xb       = (u16*)alloc((size_t)T_TOK * H_DIM * 2);            //  4 MiB
  u16* wgu_t    = (u16*)alloc((size_t)NEXP * 1024 * 1024 * 2);       // 32 MiB
  u16* wd_t     = (u16*)alloc((size_t)NEXP * 1024 * 512 * 2);        // 16 MiB
  u16* wsgu_t   = (u16*)alloc((size_t)2048 * 1024 * 2);              //  4 MiB
  u16* wsd_t    = (u16*)alloc((size_t)1024 * 1024 * 2);              //  2 MiB
  u16* act_r    = (u16*)alloc((size_t)NEXP * CAP * I_DIM * 2);       //  6 MiB
  u16* act_s    = (u16*)alloc((size_t)T_TOK * 1024 * 2);             //  4 MiB
  int*   counts   = (int*)alloc(64);
  int*   tok_w_i  = (int*)alloc((size_t)2 * T_TOK * 4);
  int*   slot_of  = (int*)alloc((size_t)2 * T_TOK * 4);
  int*   perm_tok = (int*)alloc((size_t)NEXP * CAP * 4);
  float* tok_w = (float*)tok_w_i;
  // alias: down_r (16x384 rows x 1024 f32 = 24 MiB) reuses wgu_t, whose last
  // reader is the GU GEMM that strictly precedes the DOWN GEMM on this stream.
  float* down_r = (float*)wgu_t;
  if (off > ws_size) return;   // fail loudly rather than corrupt

  hipMemsetAsync(counts, 0, 64, stream);
  convert_kernel<<<7424, 256, 0, stream>>>(x, w_gate, w_up, w_down, wsg, wsu, wsd,
                                           xb, wgu_t, wd_t, wsgu_t, wsd_t);
  router_kernel<<<128, 256, 0, stream>>>(x, gate_w, perm_tok, slot_of, tok_w, counts);
  // fused gate|up + SwiGLU: routed -> act_r, shared -> act_s (no gu intermediate)
  gemm_fused_kernel<true><<<640, 256, 0, stream>>>(
      xb, xb, wsgu_t, wgu_t, act_s, act_r, nullptr, nullptr, counts, perm_tok);
  // fused down: routed (A=act_r, B=wd_t, O=down_r) + shared (A=act_s, B=wsd_t, O=out)
  gemm_fused_kernel<false><<<512, 256, 0, stream>>>(
      act_s, act_r, wsd_t, wd_t, nullptr, nullptr, out, down_r, counts, perm_tok);
  combine_kernel<<<T_TOK, 256, 0, stream>>>(out, down_r, slot_of, tok_w);
}